// Round 2
// baseline (69.335 us; speedup 1.0000x reference)
//
#include <hip/hip_runtime.h>
#include <hip/hip_bf16.h>
#include <stdint.h>

// Problem constants (B,S,D,K) = (2,4096,512,32)
#define S_LEN  4096
#define D_DIM  512
#define K_R    32
#define M_ROWS 8192

typedef __attribute__((ext_vector_type(8))) short bf16x8;
typedef __attribute__((ext_vector_type(4))) float f32x4;

__device__ __forceinline__ float bf2f(short u) {
  union { unsigned int i; float f; } c;
  c.i = ((unsigned int)(unsigned short)u) << 16;
  return c.f;
}

__device__ __forceinline__ void gload_lds16(const void* g, void* lds) {
  __builtin_amdgcn_global_load_lds(
      (__attribute__((address_space(1))) void*)g,
      (__attribute__((address_space(3))) void*)lds, 16, 0, 0);
}

// ---------------------------------------------------------------------------
// Kernel 1 (merged): blocks [0,2048): cast x->bf16.  blocks [2048,2304):
// WcT = (W_in @ W_out)^T in bf16 (f32 compute).
// ---------------------------------------------------------------------------
__global__ void __launch_bounds__(256) prep_kernel(
    const float* __restrict__ x, __hip_bfloat16* __restrict__ xb,
    const float* __restrict__ Win, const float* __restrict__ Wout,
    __hip_bfloat16* __restrict__ WcT) {
  __shared__ float Asm[32][33];
  __shared__ float Bsm[32][33];
  if (blockIdx.x < 2048) {
    const int i = blockIdx.x * 256 + threadIdx.x;
    const float4* xp = (const float4*)x;
    float4 v0 = xp[2 * i];
    float4 v1 = xp[2 * i + 1];
    union { __hip_bfloat16 h[8]; int4 v; } u;
    u.h[0] = __float2bfloat16(v0.x); u.h[1] = __float2bfloat16(v0.y);
    u.h[2] = __float2bfloat16(v0.z); u.h[3] = __float2bfloat16(v0.w);
    u.h[4] = __float2bfloat16(v1.x); u.h[5] = __float2bfloat16(v1.y);
    u.h[6] = __float2bfloat16(v1.z); u.h[7] = __float2bfloat16(v1.w);
    ((int4*)xb)[i] = u.v;
    return;
  }
  const int bx = blockIdx.x - 2048;
  const int i0 = (bx >> 4) * 32;    // rows of Wc
  const int j0 = (bx & 15) * 32;    // cols of Wc
  const int t  = threadIdx.x;
  const int lr = t >> 3;
  const int lc = (t & 7) * 4;
  const int oi = (t >> 4) * 2;
  const int oj = (t & 15) * 2;
  float acc00 = 0.f, acc01 = 0.f, acc10 = 0.f, acc11 = 0.f;
  for (int k0 = 0; k0 < 512; k0 += 32) {
    float4 a = *(const float4*)&Win[(size_t)(i0 + lr) * 512 + k0 + lc];
    float4 b = *(const float4*)&Wout[(size_t)(k0 + lr) * 512 + j0 + lc];
    __syncthreads();
    Asm[lr][lc] = a.x; Asm[lr][lc + 1] = a.y; Asm[lr][lc + 2] = a.z; Asm[lr][lc + 3] = a.w;
    Bsm[lr][lc] = b.x; Bsm[lr][lc + 1] = b.y; Bsm[lr][lc + 2] = b.z; Bsm[lr][lc + 3] = b.w;
    __syncthreads();
#pragma unroll
    for (int k = 0; k < 32; ++k) {
      const float a0 = Asm[oi][k], a1 = Asm[oi + 1][k];
      const float b0 = Bsm[k][oj], b1 = Bsm[k][oj + 1];
      acc00 = fmaf(a0, b0, acc00); acc01 = fmaf(a0, b1, acc01);
      acc10 = fmaf(a1, b0, acc10); acc11 = fmaf(a1, b1, acc11);
    }
  }
  WcT[(size_t)(j0 + oj) * 512 + i0 + oi]         = __float2bfloat16(acc00);
  WcT[(size_t)(j0 + oj) * 512 + i0 + oi + 1]     = __float2bfloat16(acc10);
  WcT[(size_t)(j0 + oj + 1) * 512 + i0 + oi]     = __float2bfloat16(acc01);
  WcT[(size_t)(j0 + oj + 1) * 512 + i0 + oi + 1] = __float2bfloat16(acc11);
}

// ---------------------------------------------------------------------------
// Kernel 2: g[row,:] = sum_k w[s,k] * Xb[b, routes[s,k], :]   (bf16 out)
//   4 waves/block, one row per wave, lane owns 8 bf16 (16B) of D=512.
//   XCD-chunked rows -> per-XCD gather set stays in its 4MB L2.
// ---------------------------------------------------------------------------
__global__ void __launch_bounds__(256) gather_kernel(
    const __hip_bfloat16* __restrict__ xb,
    const float* __restrict__ fw,
    const int* __restrict__ routes,
    __hip_bfloat16* __restrict__ g) {
  __shared__ float w_s[4][K_R];
  __shared__ int   r_s[4][K_R];
  const int tid = threadIdx.x;
  const int wid = tid >> 6, lane = tid & 63;
  const int lin = blockIdx.x;                      // 2048 blocks
  const int bchunk = (lin & 7) * 256 + (lin >> 3); // XCD-contiguous rows
  const int row = bchunk * 4 + wid;
  const int s = row & (S_LEN - 1);
  const int b = row >> 12;
  if (lane < K_R) {
    r_s[wid][lane] = routes[s * K_R + lane];
    w_s[wid][lane] = fw[s * K_R + lane];
  }
  __syncthreads();
  const __hip_bfloat16* xbb = xb + (size_t)b * S_LEN * D_DIM + lane * 8;
  float acc[8] = {};
#pragma unroll 8
  for (int k = 0; k < K_R; ++k) {
    const float wk = w_s[wid][k];
    const bf16x8 v = *(const bf16x8*)(xbb + (size_t)r_s[wid][k] * D_DIM);
#pragma unroll
    for (int j = 0; j < 8; ++j) acc[j] = fmaf(wk, bf2f(v[j]), acc[j]);
  }
  union { __hip_bfloat16 h[8]; int4 v; } u;
#pragma unroll
  for (int j = 0; j < 8; ++j) u.h[j] = __float2bfloat16(acc[j]);
  *(int4*)(g + (size_t)row * D_DIM + lane * 8) = u.v;
}

// ---------------------------------------------------------------------------
// Kernel 3: out = x + g @ Wc + b_out   (M=8192, N=512, K=512)
//   Tile 128x64, BK=64, 4 waves (2x2). LDS XOR-swizzle (unit ^= row&7) applied
//   on BOTH sides: pre-swizzled global source for global_load_lds + swizzled
//   ds_read address (rule #21) -> conflict-free ds_read_b128.
// ---------------------------------------------------------------------------
#define BM 128
#define BN 64
#define BK 64

__global__ void __launch_bounds__(256) gemm_out_kernel(
    const __hip_bfloat16* __restrict__ A,    // g (M x 512)
    const __hip_bfloat16* __restrict__ BT,   // WcT (n x k)
    const float* __restrict__ x,
    const float* __restrict__ b_out,
    float* __restrict__ out) {
  __shared__ __hip_bfloat16 As[BM][BK];   // 16 KB
  __shared__ __hip_bfloat16 Bs[BN][BK];   //  8 KB
  const int tid = threadIdx.x;
  const int w = tid >> 6, l = tid & 63;

  // XCD-chunked swizzle; same chunking as gather_kernel so g rows are L2-hot.
  const int lin = blockIdx.x;
  const int id2 = (lin & 7) * 64 + (lin >> 3);
  const int bm0 = (id2 >> 3) * BM;    // 64 m-tiles
  const int bn0 = (id2 & 7) * BN;     // 8 n-tiles

  const int wr  = (w >> 1) * 64;      // wave row
  const int wcn = (w & 1) * 32;       // wave col

  // staging: lane l -> row (l>>3), stored unit (l&7); source unit (l&7)^(l>>3)
  const int rin = l >> 3;
  const int usw = (l & 7) ^ rin;
  const __hip_bfloat16* gA = A + (size_t)(bm0 + w * 8 + rin) * D_DIM + usw * 8;
  const __hip_bfloat16* gB = BT + (size_t)(bn0 + w * 8 + rin) * D_DIM + usw * 8;
  __hip_bfloat16* ldsA = &As[w * 8][0];
  __hip_bfloat16* ldsB = &Bs[w * 8][0];

  const int fr = l & 15;
  const int fq = l >> 4;

  f32x4 acc[4][2] = {};

  for (int k0 = 0; k0 < D_DIM; k0 += BK) {
#pragma unroll
    for (int i = 0; i < 4; ++i)
      gload_lds16(gA + (size_t)(i * 32) * D_DIM + k0, ldsA + i * 32 * BK);
#pragma unroll
    for (int j = 0; j < 2; ++j)
      gload_lds16(gB + (size_t)(j * 32) * D_DIM + k0, ldsB + j * 32 * BK);
    __syncthreads();   // compiler drains vmcnt(0) before s_barrier
#pragma unroll
    for (int kk = 0; kk < 2; ++kk) {
      const int u = (kk * 4 + fq) ^ (fr & 7);   // swizzled 16B unit
      bf16x8 af[4], bfv[2];
#pragma unroll
      for (int m = 0; m < 4; ++m)
        af[m] = *(const bf16x8*)&As[wr + m * 16 + fr][u * 8];
#pragma unroll
      for (int n = 0; n < 2; ++n)
        bfv[n] = *(const bf16x8*)&Bs[wcn + n * 16 + fr][u * 8];
#pragma unroll
      for (int m = 0; m < 4; ++m)
#pragma unroll
        for (int n = 0; n < 2; ++n)
          acc[m][n] = __builtin_amdgcn_mfma_f32_16x16x32_bf16(af[m], bfv[n], acc[m][n], 0, 0, 0);
    }
    __syncthreads();
  }

  // epilogue: out = acc + x + b_out   (C/D layout: col=lane&15, row=fq*4+reg)
  const float bb0 = b_out[bn0 + wcn + fr];
  const float bb1 = b_out[bn0 + wcn + 16 + fr];
#pragma unroll
  for (int m = 0; m < 4; ++m)
#pragma unroll
    for (int r = 0; r < 4; ++r) {
      const int grow = bm0 + wr + m * 16 + fq * 4 + r;
      const size_t base = (size_t)grow * D_DIM + bn0 + wcn + fr;
      out[base]      = acc[m][0][r] + x[base]      + bb0;
      out[base + 16] = acc[m][1][r] + x[base + 16] + bb1;
    }
}

// ---------------------------------------------------------------------------
extern "C" void kernel_launch(void* const* d_in, const int* in_sizes, int n_in,
                              void* d_out, int out_size, void* d_ws, size_t ws_size,
                              hipStream_t stream) {
  const float* x      = (const float*)d_in[0];
  const float* W_in   = (const float*)d_in[1];
  const float* W_out  = (const float*)d_in[2];
  const float* b_out  = (const float*)d_in[3];
  const float* fw     = (const float*)d_in[4];
  const int*   routes = (const int*)d_in[5];
  float* out = (float*)d_out;

  // workspace: Xb (8MB) | WcT (512KB) | g (8MB)
  char* ws = (char*)d_ws;
  __hip_bfloat16* Xb  = (__hip_bfloat16*)ws;
  __hip_bfloat16* WcT = (__hip_bfloat16*)(ws + 8388608);
  __hip_bfloat16* g   = (__hip_bfloat16*)(ws + 8912896);

  // 1) cast x->bf16 (2048 blocks) + WcT (256 blocks), independent work merged
  prep_kernel<<<2304, 256, 0, stream>>>(x, Xb, W_in, W_out, WcT);
  // 2) gather-fuse on bf16 rows: g = A @ Xb
  gather_kernel<<<2048, 256, 0, stream>>>(Xb, fw, routes, g);
  // 3) out = x + g @ Wc + b_out  (residual+bias fused epilogue)
  gemm_out_kernel<<<512, 256, 0, stream>>>(g, WcT, x, b_out, out);
}

// Round 3
// 44.409 us; speedup vs baseline: 1.5613x; 1.5613x over previous
//
#include <hip/hip_runtime.h>
#include <hip/hip_bf16.h>
#include <stdint.h>

// Problem constants (B,S,D,K) = (2,4096,512,32)
#define S_LEN  4096
#define D_DIM  512
#define K_R    32
#define M_ROWS 8192

typedef __attribute__((ext_vector_type(8))) short bf16x8;
typedef __attribute__((ext_vector_type(4))) float f32x4;

__device__ __forceinline__ float bf2f(short u) {
  union { unsigned int i; float f; } c;
  c.i = ((unsigned int)(unsigned short)u) << 16;
  return c.f;
}

__device__ __forceinline__ void gload_lds16(const void* g, void* lds) {
  __builtin_amdgcn_global_load_lds(
      (__attribute__((address_space(1))) void*)g,
      (__attribute__((address_space(3))) void*)lds, 16, 0, 0);
}

__device__ __forceinline__ int4 pack8(float4 v0, float4 v1) {
  union { __hip_bfloat16 h[8]; int4 v; } u;
  u.h[0] = __float2bfloat16(v0.x); u.h[1] = __float2bfloat16(v0.y);
  u.h[2] = __float2bfloat16(v0.z); u.h[3] = __float2bfloat16(v0.w);
  u.h[4] = __float2bfloat16(v1.x); u.h[5] = __float2bfloat16(v1.y);
  u.h[6] = __float2bfloat16(v1.z); u.h[7] = __float2bfloat16(v1.w);
  return u.v;
}

// ---------------------------------------------------------------------------
// Kernel 1 (prep): blocks [0,2048): cast x->bf16.
//                  blocks [2048,2112): cast W_in->bf16 (Winb).
//                  blocks [2112,2176): transpose-cast W_out -> WoutTb.
// ---------------------------------------------------------------------------
__global__ void __launch_bounds__(256) prep_kernel(
    const float* __restrict__ x, __hip_bfloat16* __restrict__ xb,
    const float* __restrict__ Win, __hip_bfloat16* __restrict__ Winb,
    const float* __restrict__ Wout, __hip_bfloat16* __restrict__ WoutTb) {
  __shared__ __hip_bfloat16 Lds[64][66];   // stride 66 -> conflict-free cols
  const int tid = threadIdx.x;
  if (blockIdx.x < 2048) {
    const int i = blockIdx.x * 256 + tid;
    const float4* xp = (const float4*)x;
    ((int4*)xb)[i] = pack8(xp[2 * i], xp[2 * i + 1]);
    return;
  }
  if (blockIdx.x < 2112) {   // Win cast: 64 blocks x 256 thr x 16 elems
    const int e4 = ((blockIdx.x - 2048) * 256 + tid) * 4;  // in float4 units
    const float4* wp = (const float4*)Win;
    int4* op = (int4*)Winb;
#pragma unroll
    for (int h = 0; h < 2; ++h)
      op[e4 / 2 + h] = pack8(wp[e4 + 2 * h], wp[e4 + 2 * h + 1]);
    return;
  }
  // transpose-cast: 64 blocks, 64x64 tile.  WoutTb[j][i] = Wout[i][j]
  const int bx = blockIdx.x - 2112;
  const int tr = (bx >> 3) * 64;   // row base in Wout
  const int tc = (bx & 7) * 64;    // col base in Wout
#pragma unroll
  for (int it = 0; it < 4; ++it) {
    const int id = it * 256 + tid;          // [0,1024)
    const int r = id >> 4, c4 = (id & 15) * 4;
    const float4 v = *(const float4*)&Wout[(size_t)(tr + r) * 512 + tc + c4];
    Lds[r][c4]     = __float2bfloat16(v.x);
    Lds[r][c4 + 1] = __float2bfloat16(v.y);
    Lds[r][c4 + 2] = __float2bfloat16(v.z);
    Lds[r][c4 + 3] = __float2bfloat16(v.w);
  }
  __syncthreads();
#pragma unroll
  for (int it = 0; it < 2; ++it) {
    const int id = it * 256 + tid;          // [0,512)
    const int j = id >> 3, i0 = (id & 7) * 8;
    union { __hip_bfloat16 h[8]; int4 v; } u;
#pragma unroll
    for (int r = 0; r < 8; ++r) u.h[r] = Lds[i0 + r][j];
    *(int4*)&WoutTb[(size_t)(tc + j) * 512 + tr + i0] = u.v;
  }
}

// ---------------------------------------------------------------------------
// Kernel 2 (mid): blocks [0,2048): gather  g[row,:] = sum_k w[s,k]*Xb[b,route,:]
//                 blocks [2048,2080): wcgemm  WcT = WoutTb @ Win  (bf16 out)
//   Independent work merged so the 32-block wcgemm hides under the gather.
// ---------------------------------------------------------------------------
#define BM 128
#define BN 64
#define BK 64

__global__ void __launch_bounds__(256) mid_kernel(
    const __hip_bfloat16* __restrict__ xb,
    const float* __restrict__ fw,
    const int* __restrict__ routes,
    __hip_bfloat16* __restrict__ g,
    const __hip_bfloat16* __restrict__ WoutTb,   // A  (m=j, k=p)
    const __hip_bfloat16* __restrict__ Winb,     // BT (n=q, k=p)
    __hip_bfloat16* __restrict__ WcT) {
  __shared__ __hip_bfloat16 As[BM][BK];   // 16 KB
  __shared__ __hip_bfloat16 Bs[BN][BK];   //  8 KB
  __shared__ float w_s[4][K_R];
  __shared__ int   r_s[4][K_R];
  const int tid = threadIdx.x;
  const int w = tid >> 6, l = tid & 63;

  if (blockIdx.x < 2048) {
    // ---- gather path ----
    const int lin = blockIdx.x;
    const int bchunk = (lin & 7) * 256 + (lin >> 3); // XCD-contiguous rows
    const int row = bchunk * 4 + w;
    const int s = row & (S_LEN - 1);
    const int b = row >> 12;
    if (l < K_R) {
      r_s[w][l] = routes[s * K_R + l];
      w_s[w][l] = fw[s * K_R + l];
    }
    __syncthreads();
    const __hip_bfloat16* xbb = xb + (size_t)b * S_LEN * D_DIM + l * 8;
    float acc[8] = {};
#pragma unroll 8
    for (int k = 0; k < K_R; ++k) {
      const float wk = w_s[w][k];
      const bf16x8 v = *(const bf16x8*)(xbb + (size_t)r_s[w][k] * D_DIM);
#pragma unroll
      for (int j = 0; j < 8; ++j) acc[j] = fmaf(wk, bf2f(v[j]), acc[j]);
    }
    union { __hip_bfloat16 h[8]; int4 v; } u;
#pragma unroll
    for (int j = 0; j < 8; ++j) u.h[j] = __float2bfloat16(acc[j]);
    *(int4*)(g + (size_t)row * D_DIM + l * 8) = u.v;
    return;
  }

  // ---- wcgemm path: WcT[j][q] = sum_p WoutTb[j][p] * Winb[q][p] ----
  const int id2 = blockIdx.x - 2048;    // [0,32)
  const int bm0 = (id2 >> 3) * BM;      // 4 m-tiles (j)
  const int bn0 = (id2 & 7) * BN;       // 8 n-tiles (q)
  const int wr  = (w >> 1) * 64;
  const int wcn = (w & 1) * 32;

  const int rin = l >> 3;
  const int usw = (l & 7) ^ rin;
  const __hip_bfloat16* gA = WoutTb + (size_t)(bm0 + w * 8 + rin) * D_DIM + usw * 8;
  const __hip_bfloat16* gB = Winb   + (size_t)(bn0 + w * 8 + rin) * D_DIM + usw * 8;
  __hip_bfloat16* ldsA = &As[w * 8][0];
  __hip_bfloat16* ldsB = &Bs[w * 8][0];
  const int fr = l & 15, fq = l >> 4;

  f32x4 acc[4][2] = {};
  for (int k0 = 0; k0 < D_DIM; k0 += BK) {
#pragma unroll
    for (int i = 0; i < 4; ++i)
      gload_lds16(gA + (size_t)(i * 32) * D_DIM + k0, ldsA + i * 32 * BK);
#pragma unroll
    for (int j = 0; j < 2; ++j)
      gload_lds16(gB + (size_t)(j * 32) * D_DIM + k0, ldsB + j * 32 * BK);
    __syncthreads();
#pragma unroll
    for (int kk = 0; kk < 2; ++kk) {
      const int u = (kk * 4 + fq) ^ (fr & 7);
      bf16x8 af[4], bfv[2];
#pragma unroll
      for (int m = 0; m < 4; ++m)
        af[m] = *(const bf16x8*)&As[wr + m * 16 + fr][u * 8];
#pragma unroll
      for (int n = 0; n < 2; ++n)
        bfv[n] = *(const bf16x8*)&Bs[wcn + n * 16 + fr][u * 8];
#pragma unroll
      for (int m = 0; m < 4; ++m)
#pragma unroll
        for (int n = 0; n < 2; ++n)
          acc[m][n] = __builtin_amdgcn_mfma_f32_16x16x32_bf16(af[m], bfv[n], acc[m][n], 0, 0, 0);
    }
    __syncthreads();
  }
#pragma unroll
  for (int m = 0; m < 4; ++m)
#pragma unroll
    for (int n = 0; n < 2; ++n)
#pragma unroll
      for (int r = 0; r < 4; ++r) {
        const int grow = bm0 + wr + m * 16 + fq * 4 + r;
        const int gcol = bn0 + wcn + n * 16 + fr;
        WcT[(size_t)grow * D_DIM + gcol] = __float2bfloat16(acc[m][n][r]);
      }
}

// ---------------------------------------------------------------------------
// Kernel 3: out = x + g @ Wc + b_out   (M=8192, N=512, K=512) — unchanged R2
// ---------------------------------------------------------------------------
__global__ void __launch_bounds__(256) gemm_out_kernel(
    const __hip_bfloat16* __restrict__ A,    // g (M x 512)
    const __hip_bfloat16* __restrict__ BT,   // WcT (n x k)
    const float* __restrict__ x,
    const float* __restrict__ b_out,
    float* __restrict__ out) {
  __shared__ __hip_bfloat16 As[BM][BK];
  __shared__ __hip_bfloat16 Bs[BN][BK];
  const int tid = threadIdx.x;
  const int w = tid >> 6, l = tid & 63;

  const int lin = blockIdx.x;
  const int id2 = (lin & 7) * 64 + (lin >> 3);
  const int bm0 = (id2 >> 3) * BM;
  const int bn0 = (id2 & 7) * BN;

  const int wr  = (w >> 1) * 64;
  const int wcn = (w & 1) * 32;

  const int rin = l >> 3;
  const int usw = (l & 7) ^ rin;
  const __hip_bfloat16* gA = A + (size_t)(bm0 + w * 8 + rin) * D_DIM + usw * 8;
  const __hip_bfloat16* gB = BT + (size_t)(bn0 + w * 8 + rin) * D_DIM + usw * 8;
  __hip_bfloat16* ldsA = &As[w * 8][0];
  __hip_bfloat16* ldsB = &Bs[w * 8][0];

  const int fr = l & 15, fq = l >> 4;
  f32x4 acc[4][2] = {};

  for (int k0 = 0; k0 < D_DIM; k0 += BK) {
#pragma unroll
    for (int i = 0; i < 4; ++i)
      gload_lds16(gA + (size_t)(i * 32) * D_DIM + k0, ldsA + i * 32 * BK);
#pragma unroll
    for (int j = 0; j < 2; ++j)
      gload_lds16(gB + (size_t)(j * 32) * D_DIM + k0, ldsB + j * 32 * BK);
    __syncthreads();
#pragma unroll
    for (int kk = 0; kk < 2; ++kk) {
      const int u = (kk * 4 + fq) ^ (fr & 7);
      bf16x8 af[4], bfv[2];
#pragma unroll
      for (int m = 0; m < 4; ++m)
        af[m] = *(const bf16x8*)&As[wr + m * 16 + fr][u * 8];
#pragma unroll
      for (int n = 0; n < 2; ++n)
        bfv[n] = *(const bf16x8*)&Bs[wcn + n * 16 + fr][u * 8];
#pragma unroll
      for (int m = 0; m < 4; ++m)
#pragma unroll
        for (int n = 0; n < 2; ++n)
          acc[m][n] = __builtin_amdgcn_mfma_f32_16x16x32_bf16(af[m], bfv[n], acc[m][n], 0, 0, 0);
    }
    __syncthreads();
  }

  const float bb0 = b_out[bn0 + wcn + fr];
  const float bb1 = b_out[bn0 + wcn + 16 + fr];
#pragma unroll
  for (int m = 0; m < 4; ++m)
#pragma unroll
    for (int r = 0; r < 4; ++r) {
      const int grow = bm0 + wr + m * 16 + fq * 4 + r;
      const size_t base = (size_t)grow * D_DIM + bn0 + wcn + fr;
      out[base]      = acc[m][0][r] + x[base]      + bb0;
      out[base + 16] = acc[m][1][r] + x[base + 16] + bb1;
    }
}

// ---------------------------------------------------------------------------
extern "C" void kernel_launch(void* const* d_in, const int* in_sizes, int n_in,
                              void* d_out, int out_size, void* d_ws, size_t ws_size,
                              hipStream_t stream) {
  const float* x      = (const float*)d_in[0];
  const float* W_in   = (const float*)d_in[1];
  const float* W_out  = (const float*)d_in[2];
  const float* b_out  = (const float*)d_in[3];
  const float* fw     = (const float*)d_in[4];
  const int*   routes = (const int*)d_in[5];
  float* out = (float*)d_out;

  // workspace: Xb(8MB) | WcT(512KB) | g(8MB) | Winb(512KB) | WoutTb(512KB)
  char* ws = (char*)d_ws;
  __hip_bfloat16* Xb     = (__hip_bfloat16*)ws;
  __hip_bfloat16* WcT    = (__hip_bfloat16*)(ws + 8388608);
  __hip_bfloat16* g      = (__hip_bfloat16*)(ws + 8912896);
  __hip_bfloat16* Winb   = (__hip_bfloat16*)(ws + 17301504);
  __hip_bfloat16* WoutTb = (__hip_bfloat16*)(ws + 17825792);

  // 1) casts + transpose (all elementwise, fully parallel)
  prep_kernel<<<2176, 256, 0, stream>>>(x, Xb, W_in, Winb, W_out, WoutTb);
  // 2) gather (2048 blocks) || wcgemm via MFMA (32 blocks)
  mid_kernel<<<2080, 256, 0, stream>>>(Xb, fw, routes, g, WoutTb, Winb, WcT);
  // 3) out = x + g @ Wc + b_out
  gemm_out_kernel<<<512, 256, 0, stream>>>(g, WcT, x, b_out, out);
}

// Round 4
// 36.191 us; speedup vs baseline: 1.9158x; 1.2271x over previous
//
#include <hip/hip_runtime.h>
#include <hip/hip_bf16.h>
#include <stdint.h>

// Problem constants (B,S,D,K) = (2,4096,512,32)
#define S_LEN  4096
#define D_DIM  512
#define K_R    32
#define M_ROWS 8192

typedef __attribute__((ext_vector_type(8))) short bf16x8;
typedef __attribute__((ext_vector_type(4))) float f32x4;

__device__ __forceinline__ float bf2f(short u) {
  union { unsigned int i; float f; } c;
  c.i = ((unsigned int)(unsigned short)u) << 16;
  return c.f;
}

__device__ __forceinline__ void gload_lds16(const void* g, void* lds) {
  __builtin_amdgcn_global_load_lds(
      (__attribute__((address_space(1))) void*)g,
      (__attribute__((address_space(3))) void*)lds, 16, 0, 0);
}

__device__ __forceinline__ int4 pack8(float4 v0, float4 v1) {
  union { __hip_bfloat16 h[8]; int4 v; } u;
  u.h[0] = __float2bfloat16(v0.x); u.h[1] = __float2bfloat16(v0.y);
  u.h[2] = __float2bfloat16(v0.z); u.h[3] = __float2bfloat16(v0.w);
  u.h[4] = __float2bfloat16(v1.x); u.h[5] = __float2bfloat16(v1.y);
  u.h[6] = __float2bfloat16(v1.z); u.h[7] = __float2bfloat16(v1.w);
  return u.v;
}

// ---------------------------------------------------------------------------
// Kernel 1 (prep): blocks [0,2048): cast x->bf16.
//                  blocks [2048,2112): cast W_in->bf16 (Winb).
//                  blocks [2112,2176): transpose-cast W_out -> WoutTb.
// ---------------------------------------------------------------------------
__global__ void __launch_bounds__(256) prep_kernel(
    const float* __restrict__ x, __hip_bfloat16* __restrict__ xb,
    const float* __restrict__ Win, __hip_bfloat16* __restrict__ Winb,
    const float* __restrict__ Wout, __hip_bfloat16* __restrict__ WoutTb) {
  __shared__ __hip_bfloat16 Lds[64][66];   // stride 66 -> conflict-free cols
  const int tid = threadIdx.x;
  if (blockIdx.x < 2048) {
    const int i = blockIdx.x * 256 + tid;
    const float4* xp = (const float4*)x;
    ((int4*)xb)[i] = pack8(xp[2 * i], xp[2 * i + 1]);
    return;
  }
  if (blockIdx.x < 2112) {   // Win cast: 64 blocks x 256 thr x 16 elems
    const int e4 = ((blockIdx.x - 2048) * 256 + tid) * 4;  // in float4 units
    const float4* wp = (const float4*)Win;
    int4* op = (int4*)Winb;
#pragma unroll
    for (int h = 0; h < 2; ++h)
      op[e4 / 2 + h] = pack8(wp[e4 + 2 * h], wp[e4 + 2 * h + 1]);
    return;
  }
  // transpose-cast: 64 blocks, 64x64 tile.  WoutTb[j][i] = Wout[i][j]
  const int bx = blockIdx.x - 2112;
  const int tr = (bx >> 3) * 64;   // row base in Wout
  const int tc = (bx & 7) * 64;    // col base in Wout
#pragma unroll
  for (int it = 0; it < 4; ++it) {
    const int id = it * 256 + tid;          // [0,1024)
    const int r = id >> 4, c4 = (id & 15) * 4;
    const float4 v = *(const float4*)&Wout[(size_t)(tr + r) * 512 + tc + c4];
    Lds[r][c4]     = __float2bfloat16(v.x);
    Lds[r][c4 + 1] = __float2bfloat16(v.y);
    Lds[r][c4 + 2] = __float2bfloat16(v.z);
    Lds[r][c4 + 3] = __float2bfloat16(v.w);
  }
  __syncthreads();
#pragma unroll
  for (int it = 0; it < 2; ++it) {
    const int id = it * 256 + tid;          // [0,512)
    const int j = id >> 3, i0 = (id & 7) * 8;
    union { __hip_bfloat16 h[8]; int4 v; } u;
#pragma unroll
    for (int r = 0; r < 8; ++r) u.h[r] = Lds[i0 + r][j];
    *(int4*)&WoutTb[(size_t)(tc + j) * 512 + tr + i0] = u.v;
  }
}

// ---------------------------------------------------------------------------
// Kernel 2 (mid): blocks [0,32): wcgemm  WcT = WoutTb @ Winb^T-contract (bf16)
//                 blocks [32,2080): gather g[row,:] = sum_k w[s,k]*Xb[b,route,:]
//   wcgemm FIRST so it overlaps the gather body instead of forming a tail.
// ---------------------------------------------------------------------------
#define BM 128
#define BN 64
#define BK 64

__global__ void __launch_bounds__(256) mid_kernel(
    const __hip_bfloat16* __restrict__ xb,
    const float* __restrict__ fw,
    const int* __restrict__ routes,
    __hip_bfloat16* __restrict__ g,
    const __hip_bfloat16* __restrict__ WoutTb,   // A  (m=j, k=p)
    const __hip_bfloat16* __restrict__ Winb,     // BT (n=q, k=p)
    __hip_bfloat16* __restrict__ WcT) {
  __shared__ __hip_bfloat16 As[BM][BK];   // 16 KB
  __shared__ __hip_bfloat16 Bs[BN][BK];   //  8 KB
  __shared__ float w_s[4][K_R];
  __shared__ int   r_s[4][K_R];
  const int tid = threadIdx.x;
  const int w = tid >> 6, l = tid & 63;

  if (blockIdx.x >= 32) {
    // ---- gather path ----
    const int lin = blockIdx.x - 32;
    const int bchunk = (lin & 7) * 256 + (lin >> 3); // XCD-contiguous rows
    const int row = bchunk * 4 + w;
    const int s = row & (S_LEN - 1);
    const int b = row >> 12;
    if (l < K_R) {
      r_s[w][l] = routes[s * K_R + l];
      w_s[w][l] = fw[s * K_R + l];
    }
    __syncthreads();
    const __hip_bfloat16* xbb = xb + (size_t)b * S_LEN * D_DIM + l * 8;
    float acc[8] = {};
#pragma unroll 8
    for (int k = 0; k < K_R; ++k) {
      const float wk = w_s[w][k];
      const bf16x8 v = *(const bf16x8*)(xbb + (size_t)r_s[w][k] * D_DIM);
#pragma unroll
      for (int j = 0; j < 8; ++j) acc[j] = fmaf(wk, bf2f(v[j]), acc[j]);
    }
    union { __hip_bfloat16 h[8]; int4 v; } u;
#pragma unroll
    for (int j = 0; j < 8; ++j) u.h[j] = __float2bfloat16(acc[j]);
    *(int4*)(g + (size_t)row * D_DIM + l * 8) = u.v;
    return;
  }

  // ---- wcgemm path: WcT[j][q] = sum_p WoutTb[j][p] * Winb[q][p] ----
  const int id2 = blockIdx.x;           // [0,32)
  const int bm0 = (id2 >> 3) * BM;      // 4 m-tiles (j)
  const int bn0 = (id2 & 7) * BN;       // 8 n-tiles (q)
  const int wr  = (w >> 1) * 64;
  const int wcn = (w & 1) * 32;

  const int rin = l >> 3;
  const int usw = (l & 7) ^ rin;
  const __hip_bfloat16* gA = WoutTb + (size_t)(bm0 + w * 8 + rin) * D_DIM + usw * 8;
  const __hip_bfloat16* gB = Winb   + (size_t)(bn0 + w * 8 + rin) * D_DIM + usw * 8;
  __hip_bfloat16* ldsA = &As[w * 8][0];
  __hip_bfloat16* ldsB = &Bs[w * 8][0];
  const int fr = l & 15, fq = l >> 4;

  f32x4 acc[4][2] = {};
  for (int k0 = 0; k0 < D_DIM; k0 += BK) {
#pragma unroll
    for (int i = 0; i < 4; ++i)
      gload_lds16(gA + (size_t)(i * 32) * D_DIM + k0, ldsA + i * 32 * BK);
#pragma unroll
    for (int j = 0; j < 2; ++j)
      gload_lds16(gB + (size_t)(j * 32) * D_DIM + k0, ldsB + j * 32 * BK);
    __syncthreads();
#pragma unroll
    for (int kk = 0; kk < 2; ++kk) {
      const int u = (kk * 4 + fq) ^ (fr & 7);
      bf16x8 af[4], bfv[2];
#pragma unroll
      for (int m = 0; m < 4; ++m)
        af[m] = *(const bf16x8*)&As[wr + m * 16 + fr][u * 8];
#pragma unroll
      for (int n = 0; n < 2; ++n)
        bfv[n] = *(const bf16x8*)&Bs[wcn + n * 16 + fr][u * 8];
#pragma unroll
      for (int m = 0; m < 4; ++m)
#pragma unroll
        for (int n = 0; n < 2; ++n)
          acc[m][n] = __builtin_amdgcn_mfma_f32_16x16x32_bf16(af[m], bfv[n], acc[m][n], 0, 0, 0);
    }
    __syncthreads();
  }
#pragma unroll
  for (int m = 0; m < 4; ++m)
#pragma unroll
    for (int n = 0; n < 2; ++n)
#pragma unroll
      for (int r = 0; r < 4; ++r) {
        const int grow = bm0 + wr + m * 16 + fq * 4 + r;
        const int gcol = bn0 + wcn + n * 16 + fr;
        WcT[(size_t)grow * D_DIM + gcol] = __float2bfloat16(acc[m][n][r]);
      }
}

// ---------------------------------------------------------------------------
// Kernel 3: out = x + g @ Wc + b_out   (M=8192, N=512, K=512)
//   2-phase double-buffered LDS (T3-minimum): STAGE(next) issued BEFORE the
//   current tile's ds_read+MFMA; single vmcnt-drain+barrier per K-step.
// ---------------------------------------------------------------------------
__global__ void __launch_bounds__(256) gemm_out_kernel(
    const __hip_bfloat16* __restrict__ A,    // g (M x 512)
    const __hip_bfloat16* __restrict__ BT,   // WcT (n x k)
    const float* __restrict__ x,
    const float* __restrict__ b_out,
    float* __restrict__ out) {
  __shared__ __hip_bfloat16 As[2][BM][BK];   // 32 KB
  __shared__ __hip_bfloat16 Bs[2][BN][BK];   // 16 KB
  const int tid = threadIdx.x;
  const int w = tid >> 6, l = tid & 63;

  const int lin = blockIdx.x;
  const int id2 = (lin & 7) * 64 + (lin >> 3);
  const int bm0 = (id2 >> 3) * BM;
  const int bn0 = (id2 & 7) * BN;

  const int wr  = (w >> 1) * 64;
  const int wcn = (w & 1) * 32;

  const int rin = l >> 3;
  const int usw = (l & 7) ^ rin;
  const __hip_bfloat16* gA = A + (size_t)(bm0 + w * 8 + rin) * D_DIM + usw * 8;
  const __hip_bfloat16* gB = BT + (size_t)(bn0 + w * 8 + rin) * D_DIM + usw * 8;

  const int fr = l & 15, fq = l >> 4;
  f32x4 acc[4][2] = {};

#define STAGE(buf, k0)                                                          \
  {                                                                             \
    _Pragma("unroll")                                                           \
    for (int i = 0; i < 4; ++i)                                                 \
      gload_lds16(gA + (size_t)(i * 32) * D_DIM + (k0),                         \
                  &As[buf][w * 8][0] + i * 32 * BK);                            \
    _Pragma("unroll")                                                           \
    for (int j = 0; j < 2; ++j)                                                 \
      gload_lds16(gB + (size_t)(j * 32) * D_DIM + (k0),                         \
                  &Bs[buf][w * 8][0] + j * 32 * BK);                            \
  }

#define COMPUTE(buf)                                                            \
  {                                                                             \
    _Pragma("unroll")                                                           \
    for (int kk = 0; kk < 2; ++kk) {                                            \
      const int u = (kk * 4 + fq) ^ (fr & 7);                                   \
      bf16x8 af[4], bfv[2];                                                     \
      _Pragma("unroll")                                                         \
      for (int m = 0; m < 4; ++m)                                               \
        af[m] = *(const bf16x8*)&As[buf][wr + m * 16 + fr][u * 8];              \
      _Pragma("unroll")                                                         \
      for (int n = 0; n < 2; ++n)                                               \
        bfv[n] = *(const bf16x8*)&Bs[buf][wcn + n * 16 + fr][u * 8];            \
      _Pragma("unroll")                                                         \
      for (int m = 0; m < 4; ++m)                                               \
        _Pragma("unroll")                                                       \
        for (int n = 0; n < 2; ++n)                                             \
          acc[m][n] = __builtin_amdgcn_mfma_f32_16x16x32_bf16(                  \
              af[m], bfv[n], acc[m][n], 0, 0, 0);                               \
    }                                                                           \
  }

  STAGE(0, 0);
  __syncthreads();                 // drains prologue loads (vmcnt(0) + barrier)
  int cur = 0;
#pragma unroll
  for (int t = 0; t < 7; ++t) {
    STAGE(cur ^ 1, (t + 1) * BK);  // issue next tile BEFORE computing current
    COMPUTE(cur);
    __syncthreads();               // drains this iter's STAGE; readers done
    cur ^= 1;
  }
  COMPUTE(cur);                    // last tile, no prefetch
#undef STAGE
#undef COMPUTE

  const float bb0 = b_out[bn0 + wcn + fr];
  const float bb1 = b_out[bn0 + wcn + 16 + fr];
#pragma unroll
  for (int m = 0; m < 4; ++m)
#pragma unroll
    for (int r = 0; r < 4; ++r) {
      const int grow = bm0 + wr + m * 16 + fq * 4 + r;
      const size_t base = (size_t)grow * D_DIM + bn0 + wcn + fr;
      out[base]      = acc[m][0][r] + x[base]      + bb0;
      out[base + 16] = acc[m][1][r] + x[base + 16] + bb1;
    }
}

// ---------------------------------------------------------------------------
extern "C" void kernel_launch(void* const* d_in, const int* in_sizes, int n_in,
                              void* d_out, int out_size, void* d_ws, size_t ws_size,
                              hipStream_t stream) {
  const float* x      = (const float*)d_in[0];
  const float* W_in   = (const float*)d_in[1];
  const float* W_out  = (const float*)d_in[2];
  const float* b_out  = (const float*)d_in[3];
  const float* fw     = (const float*)d_in[4];
  const int*   routes = (const int*)d_in[5];
  float* out = (float*)d_out;

  // workspace: Xb(8MB) | WcT(512KB) | g(8MB) | Winb(512KB) | WoutTb(512KB)
  char* ws = (char*)d_ws;
  __hip_bfloat16* Xb     = (__hip_bfloat16*)ws;
  __hip_bfloat16* WcT    = (__hip_bfloat16*)(ws + 8388608);
  __hip_bfloat16* g      = (__hip_bfloat16*)(ws + 8912896);
  __hip_bfloat16* Winb   = (__hip_bfloat16*)(ws + 17301504);
  __hip_bfloat16* WoutTb = (__hip_bfloat16*)(ws + 17825792);

  // 1) casts + transpose (all elementwise, fully parallel)
  prep_kernel<<<2176, 256, 0, stream>>>(x, Xb, W_in, Winb, W_out, WoutTb);
  // 2) wcgemm (32 blocks, first) || gather (2048 blocks)
  mid_kernel<<<2080, 256, 0, stream>>>(Xb, fw, routes, g, WoutTb, Winb, WcT);
  // 3) out = x + g @ Wc + b_out  (2-phase double-buffered)
  gemm_out_kernel<<<512, 256, 0, stream>>>(g, WcT, x, b_out, out);
}